// Round 11
// baseline (328.510 us; speedup 1.0000x reference)
//
#include <hip/hip_runtime.h>
#include <hip/hip_bf16.h>
#include <math.h>

#define LN2_F 0.69314718055994531f
#define INV_LN2_F 1.44269504088896341f
#define REGION_HALFS 2048   // one 16-row m-tile, K<=128, subtiled for tr-read (4 KB)

typedef _Float16 half8 __attribute__((ext_vector_type(8)));  // MFMA A/B frag (4 VGPRs)
typedef _Float16 h4_t __attribute__((ext_vector_type(4)));   // b64 / tr-read payload
typedef __fp16 pk2_t __attribute__((ext_vector_type(2)));    // cvt_pkrtz native type
typedef __attribute__((ext_vector_type(4))) float f32x4;     // MFMA C/D frag
typedef __attribute__((ext_vector_type(8))) short short8;

#define MFMA16(a, b, c) __builtin_amdgcn_mfma_f32_16x16x32_f16((a), (b), (c), 0, 0, 0)

// ---------------- weight prep: fp32 W -> f16 in B-fragment order ----------------
// B frag (mfma_f32_16x16x32_f16): lane l holds B[k = s*32 + (l>>4)*8 + j][n = ct*16 + (l&15)]
// ws layout (shorts): chunk cp = s*NT + ct at [cp*512 + lane*8 + j]. Layer bases:
// L0=0 (64x128,NT8), L1=8192 (128x128,NT8), L2=24576 (128x64,NT4), L3=32768 (64x32,NT2).
__global__ void prep_weights(const float* __restrict__ W0, const float* __restrict__ W1,
                             const float* __restrict__ W2, const float* __restrict__ W3,
                             short* __restrict__ ws) {
    int e = blockIdx.x * 256 + threadIdx.x;     // unit id, 4352 total
    const float* W; int N, NT, base, ul;
    if (e < 1024)      { W = W0; N = 128; NT = 8; base = 0;     ul = e; }
    else if (e < 3072) { W = W1; N = 128; NT = 8; base = 8192;  ul = e - 1024; }
    else if (e < 4096) { W = W2; N = 64;  NT = 4; base = 24576; ul = e - 3072; }
    else if (e < 4352) { W = W3; N = 32;  NT = 2; base = 32768; ul = e - 4096; }
    else return;
    const int cp = ul >> 6, lane = ul & 63;
    const int s = cp / NT, ct = cp % NT;
    const int k0 = s * 32 + (lane >> 4) * 8;
    const int n = ct * 16 + (lane & 15);
    union { half8 h; short8 s; } v;
#pragma unroll
    for (int j = 0; j < 8; ++j) v.h[j] = (_Float16)W[(size_t)(k0 + j) * N + n];
    *(short8*)(ws + base + cp * 512 + lane * 8) = v.s;
}

// ---------------- activation LDS tile (per 16-row m-tile) — VERIFIED r3..r10 ----------------
// Element (row, k) at half-index (k>>2)*64 + (k&3)*16 + row.
// Store: lane (q,m) writes D rows q*4..q*4+3 of col ct*16+m as ONE ds_write_b64 at
//   ct*256 + (m>>2)*64 + (m&3)*16 + q*4.
// Read: ds_read_b64_tr_b16 at byte addr base + s*1024 + q*256 + m*8 (+offset:128)
//   delivers A[m][s*32 + q*8 + j], j=0..7.

__device__ __forceinline__ void lds_fence() {
    asm volatile("s_waitcnt lgkmcnt(0)" ::: "memory");
}

__device__ __forceinline__ half8 tr_read_ks(const _Float16* region, unsigned lane_off, int s) {
    h4_t lo, hi;
    asm volatile("ds_read_b64_tr_b16 %0, %2\n\t"
                 "ds_read_b64_tr_b16 %1, %2 offset:128"
                 : "=&v"(lo), "=&v"(hi)
                 : "v"((unsigned)(uintptr_t)region + lane_off + (unsigned)(s * 1024))
                 : "memory");
    return __builtin_shufflevector(lo, hi, 0, 1, 2, 3, 4, 5, 6, 7);
}

__device__ __forceinline__ void store_tile(_Float16* __restrict__ region, int ct_global,
                                           int m, int q, f32x4 v) {
    const int base = ct_global * 256 + (m >> 2) * 64 + (m & 3) * 16 + q * 4;
    pk2_t p0 = __builtin_amdgcn_cvt_pkrtz(v[0], v[1]);
    pk2_t p1 = __builtin_amdgcn_cvt_pkrtz(v[2], v[3]);
    h4_t h = {(_Float16)p0[0], (_Float16)p0[1], (_Float16)p1[0], (_Float16)p1[1]};
    h = __builtin_elementwise_max(h, (h4_t)(_Float16)0.0f);   // relu: 2x v_pk_max_f16
    *(h4_t*)(region + base) = h;       // ds_write_b64
}

// ---------------- half-layer: NC col-tiles (<=4), 2 m-tiles share every B fragment ----------
// acc[2][NC] is the ONLY live accumulator (32 AGPR max). Biases loaded just-in-time
// (L2-hot). B frags loaded per-slice (compiler schedules these fine — r6).
template <int NK, int NT, int NC>
__device__ __forceinline__ void layer_half(const half8* __restrict__ wf,
                                           const float* __restrict__ bias, int ct0,
                                           const half8 (&af)[2][4], int lane, int m,
                                           f32x4 (&acc)[2][4]) {
#pragma unroll
    for (int c = 0; c < NC; ++c) {
        const float b = bias[(ct0 + c) * 16 + m];
        acc[0][c] = f32x4{b, b, b, b};
        acc[1][c] = f32x4{b, b, b, b};
    }
#pragma unroll
    for (int s = 0; s < NK; ++s) {
        half8 bf[4];
#pragma unroll
        for (int c = 0; c < NC; ++c) bf[c] = wf[(s * NT + ct0 + c) * 64 + lane];
#pragma unroll
        for (int c = 0; c < NC; ++c) {
            acc[0][c] = MFMA16(af[0][s], bf[c], acc[0][c]);
            acc[1][c] = MFMA16(af[1][s], bf[c], acc[1][c]);
        }
    }
}

// R11: grid = 1024 blocks = EXACTLY 4 blocks/CU, each looping over 2 chunks.
// All resident from t0, finish together -> constant ~16 waves/CU residency instead of
// the ramped 8-sequential-blocks/CU schedule (realized 35% of a 62.5% ceiling, r7/r9/r10:
// measured occupancy ~ 56% of ceiling, and dur tracks residency — the one consistent lever).
__global__ __launch_bounds__(256, 4) void mlp_phi_mfma(
    const float* __restrict__ u,
    const float* __restrict__ b0, const float* __restrict__ b1,
    const float* __restrict__ b2, const float* __restrict__ b3,
    const short* __restrict__ ws,
    const float* __restrict__ var1, const float* __restrict__ var2,
    const float* __restrict__ var3, const float* __restrict__ var4,
    const float* __restrict__ var5, const float* __restrict__ var6,
    float* __restrict__ out, int nchunks) {
    // 4 waves/block, each wave owns 32 rows per chunk (two 16-row m-tiles) end-to-end.
    // No __syncthreads anywhere. LDS: 4 waves x 2 m-tile regions x 4 KB = 32 KB.
    __shared__ __align__(16) _Float16 lds[4 * 2 * REGION_HALFS];
    const int t = threadIdx.x, lane = t & 63, wave = t >> 6;
    const int m = lane & 15, q = lane >> 4;
    _Float16* lw = lds + wave * 2 * REGION_HALFS;
    const unsigned lane_rd = (unsigned)(q * 256 + m * 8);   // tr-read per-lane byte offset

    const half8* wf0 = (const half8*)(ws);
    const half8* wf1 = (const half8*)(ws + 8192);
    const half8* wf2 = (const half8*)(ws + 24576);
    const half8* wf3 = (const half8*)(ws + 32768);

    half8 af[2][4];
    f32x4 acc[2][4];

#pragma unroll 1
    for (int c = blockIdx.x; c < nchunks; c += gridDim.x) {
        const size_t row0 = (size_t)c * 128 + wave * 32;

        // ---- Layer 0 A-frags straight from global u (L3-hot), cvt_pkrtz fp32->f16 ----
#pragma unroll
        for (int mt = 0; mt < 2; ++mt) {
            const float* up = u + (row0 + mt * 16 + m) * 64;
#pragma unroll
            for (int s = 0; s < 2; ++s) {
                float4 v0a = *(const float4*)(up + s * 32 + q * 8);
                float4 v1a = *(const float4*)(up + s * 32 + q * 8 + 4);
                pk2_t p0 = __builtin_amdgcn_cvt_pkrtz(v0a.x, v0a.y);
                pk2_t p1 = __builtin_amdgcn_cvt_pkrtz(v0a.z, v0a.w);
                pk2_t p2 = __builtin_amdgcn_cvt_pkrtz(v1a.x, v1a.y);
                pk2_t p3 = __builtin_amdgcn_cvt_pkrtz(v1a.z, v1a.w);
                af[mt][s] = half8{(_Float16)p0[0], (_Float16)p0[1], (_Float16)p1[0], (_Float16)p1[1],
                                  (_Float16)p2[0], (_Float16)p2[1], (_Float16)p3[0], (_Float16)p3[1]};
            }
        }

        // ---- Layer 0 (64 -> 128) in two 64-col halves ----
#pragma unroll
        for (int h = 0; h < 2; ++h) {
            layer_half<2, 8, 4>(wf0, b0, h * 4, af, lane, m, acc);
#pragma unroll
            for (int mt = 0; mt < 2; ++mt)
#pragma unroll
                for (int cc = 0; cc < 4; ++cc)
                    store_tile(lw + mt * REGION_HALFS, h * 4 + cc, m, q, acc[mt][cc]);
        }
        lds_fence();
#pragma unroll
        for (int mt = 0; mt < 2; ++mt)
#pragma unroll
            for (int s = 0; s < 4; ++s) af[mt][s] = tr_read_ks(lw + mt * REGION_HALFS, lane_rd, s);
        lds_fence();
        __builtin_amdgcn_sched_barrier(0);   // rule 18: MFMA must not hoist above the wait

        // ---- Layer 1 (128 -> 128) in two 64-col halves ----
#pragma unroll
        for (int h = 0; h < 2; ++h) {
            layer_half<4, 8, 4>(wf1, b1, h * 4, af, lane, m, acc);
#pragma unroll
            for (int mt = 0; mt < 2; ++mt)
#pragma unroll
                for (int cc = 0; cc < 4; ++cc)
                    store_tile(lw + mt * REGION_HALFS, h * 4 + cc, m, q, acc[mt][cc]);
        }
        lds_fence();
#pragma unroll
        for (int mt = 0; mt < 2; ++mt)
#pragma unroll
            for (int s = 0; s < 4; ++s) af[mt][s] = tr_read_ks(lw + mt * REGION_HALFS, lane_rd, s);
        lds_fence();
        __builtin_amdgcn_sched_barrier(0);

        // ---- Layer 2 (128 -> 64): single half (NT=4) ----
        layer_half<4, 4, 4>(wf2, b2, 0, af, lane, m, acc);
#pragma unroll
        for (int mt = 0; mt < 2; ++mt)
#pragma unroll
            for (int cc = 0; cc < 4; ++cc)
                store_tile(lw + mt * REGION_HALFS, cc, m, q, acc[mt][cc]);
        lds_fence();
#pragma unroll
        for (int mt = 0; mt < 2; ++mt)
#pragma unroll
            for (int s = 0; s < 2; ++s) af[mt][s] = tr_read_ks(lw + mt * REGION_HALFS, lane_rd, s);
        lds_fence();
        __builtin_amdgcn_sched_barrier(0);

        // ---- Layer 3 (64 -> 32): net stays in registers (acc[mt][0..1]) ----
        layer_half<2, 2, 2>(wf3, b3, 0, af, lane, m, acc);

        // ---- Epilogue: lane holds net[row=mt*16+q*4+r][col=ot*16+m] ----
        // log2-domain: L = log2(1-u), ln2 folded into per-d constants; exp(-x) == omu
        // exactly (x = -log(1-u)) -> no __expf in the E1 large-x branch.
        // u in [1e-4, 1-1e-4] => all quantities finite in fp32 (nan_to_num is a no-op).
#pragma unroll
        for (int ot = 0; ot < 2; ++ot) {
            const int d = ot * 16 + m;
            const float v1 = var1[d], v6 = var6[d];
            const float v2p = var2[d] * INV_LN2_F;          // v2/ln2
            const float v4 = var4[d];
            const float v4p = v4 * INV_LN2_F;               // v4/ln2
            const float v5h = 0.5f * var5[d];
            const float v5hp = v5h * INV_LN2_F;             // v5h/ln2
            const float c3 = var3[d] - v4 - v5h;            // li coefficient
#pragma unroll
            for (int mt = 0; mt < 2; ++mt) {
                float ue[4];
#pragma unroll
                for (int r = 0; r < 4; ++r)
                    ue[r] = u[(row0 + mt * 16 + q * 4 + r) * 64 + d];
#pragma unroll
                for (int r = 0; r < 4; ++r) {
                    const size_t row = row0 + mt * 16 + q * 4 + r;
                    const float net = acc[mt][ot][r];
                    const float ud = ue[r];

                    const float omu = 1.0f - ud;
                    const float L = __log2f(omu);              // log2(1-u) < 0
                    const float x = -L * LN2_F;                // -log(1-u), in (1e-4, 9.3)
                    const float RL = __builtin_amdgcn_rcpf(L); // 1/log2(1-u)

                    // E1 via Abramowitz-Stegun 5.1.53 (x<1) / 5.1.54 (x>=1)
                    const float e1s = -__log2f(x) * LN2_F
                        + (-0.57721566f + x * (0.99999193f + x * (-0.24991055f
                        + x * (0.05519968f + x * (-0.00976004f + x * 0.00107857f)))));
                    const float num = 0.2677737343f + x * (8.6347608925f + x * (18.0590169730f
                        + x * (8.5733287401f + x)));
                    const float den = 3.9584969228f + x * (21.0996530827f + x * (25.6329561486f
                        + x * (9.5733223454f + x)));
                    const float e1l = omu * num * __builtin_amdgcn_rcpf(x * den);  // exp(-x)=omu
                    const float li = -((x < 1.0f) ? e1s : e1l); // _li(1-u)

                    // phi = (v4*omu+v2)/lt + v5h*omu*(lt+1)/lt^2 + c3*li, log2 domain
                    const float phi = fmaf(v4p, omu, v2p) * RL
                                    + (v5hp * omu * (L + INV_LN2_F)) * RL * RL
                                    + c3 * li;

                    const float ud2 = ud * ud;
                    const float ud4 = ud2 * ud2;
                    const float p01 = ud4 * fmaf(-4.0f, ud, 5.0f);   // 5u^4 - 4u^5
                    const float corr1 = p01 * (v1 + phi);
                    const float d1 = ud - 1.0f;
                    const float corr2 = v6 * ud * d1 * d1;           // u^3 - 2u^2 + u

                    const float nt = fmaxf(net + corr1 + corr2, 0.0f);
                    const float base = fmaf(-0.5f, ud2, 0.5f);       // (1-u^2)/2
                    // base^(-nt) = exp2(-nt * log2(base)); v_exp_f32 is native exp2
                    out[row * 32 + d] = __builtin_amdgcn_exp2f(-nt * __log2f(base));
                }
            }
        }
    }
}

extern "C" void kernel_launch(void* const* d_in, const int* in_sizes, int n_in,
                              void* d_out, int out_size, void* d_ws, size_t ws_size,
                              hipStream_t stream) {
    const float* u    = (const float*)d_in[0];
    const float* W0   = (const float*)d_in[1];
    const float* b0   = (const float*)d_in[2];
    const float* W1   = (const float*)d_in[3];
    const float* b1   = (const float*)d_in[4];
    const float* W2   = (const float*)d_in[5];
    const float* b2   = (const float*)d_in[6];
    const float* W3   = (const float*)d_in[7];
    const float* b3   = (const float*)d_in[8];
    const float* var1 = (const float*)d_in[9];
    const float* var2 = (const float*)d_in[10];
    const float* var3 = (const float*)d_in[11];
    const float* var4 = (const float*)d_in[12];
    const float* var5 = (const float*)d_in[13];
    const float* var6 = (const float*)d_in[14];
    float* out = (float*)d_out;
    short* ws = (short*)d_ws;   // needs 69,632 B

    // Convert weights to f16 fragment layout (same work every launch).
    prep_weights<<<dim3(17), dim3(256), 0, stream>>>(W0, W1, W2, W3, ws);

    const int B = in_sizes[0] / 64;        // 262144 rows
    const int nchunks = B / 128;           // 2048 chunks of 128 rows
    // 1024 blocks = exactly 4 blocks/CU resident for the whole kernel (2 chunks each).
    const int nblocks = nchunks < 1024 ? nchunks : 1024;
    mlp_phi_mfma<<<dim3(nblocks), dim3(256), 0, stream>>>(
        u, b0, b1, b2, b3, ws,
        var1, var2, var3, var4, var5, var6, out, nchunks);
}

// Round 13
// 150.931 us; speedup vs baseline: 2.1766x; 2.1766x over previous
//
#include <hip/hip_runtime.h>
#include <hip/hip_bf16.h>
#include <math.h>

#define LN2_F 0.69314718055994531f
#define INV_LN2_F 1.44269504088896341f
#define REGION_HALFS 2048   // one 16-row m-tile, K<=128, subtiled for tr-read (4 KB)

typedef _Float16 half8 __attribute__((ext_vector_type(8)));  // MFMA A/B frag (4 VGPRs)
typedef _Float16 h4_t __attribute__((ext_vector_type(4)));   // b64 / tr-read payload
typedef __fp16 pk2_t __attribute__((ext_vector_type(2)));    // cvt_pkrtz native type
typedef __attribute__((ext_vector_type(4))) float f32x4;     // MFMA C/D frag
typedef __attribute__((ext_vector_type(8))) short short8;

#define MFMA16(a, b, c) __builtin_amdgcn_mfma_f32_16x16x32_f16((a), (b), (c), 0, 0, 0)

// ---------------- weight prep: fp32 W -> f16 in B-fragment order ----------------
// B frag (mfma_f32_16x16x32_f16): lane l holds B[k = s*32 + (l>>4)*8 + j][n = ct*16 + (l&15)]
// ws layout (shorts): chunk cp = s*NT + ct at [cp*512 + lane*8 + j]. Layer bases:
// L0=0 (64x128,NT8), L1=8192 (128x128,NT8), L2=24576 (128x64,NT4), L3=32768 (64x32,NT2).
__global__ void prep_weights(const float* __restrict__ W0, const float* __restrict__ W1,
                             const float* __restrict__ W2, const float* __restrict__ W3,
                             short* __restrict__ ws) {
    int e = blockIdx.x * 256 + threadIdx.x;     // unit id, 4352 total
    const float* W; int N, NT, base, ul;
    if (e < 1024)      { W = W0; N = 128; NT = 8; base = 0;     ul = e; }
    else if (e < 3072) { W = W1; N = 128; NT = 8; base = 8192;  ul = e - 1024; }
    else if (e < 4096) { W = W2; N = 64;  NT = 4; base = 24576; ul = e - 3072; }
    else if (e < 4352) { W = W3; N = 32;  NT = 2; base = 32768; ul = e - 4096; }
    else return;
    const int cp = ul >> 6, lane = ul & 63;
    const int s = cp / NT, ct = cp % NT;
    const int k0 = s * 32 + (lane >> 4) * 8;
    const int n = ct * 16 + (lane & 15);
    union { half8 h; short8 s; } v;
#pragma unroll
    for (int j = 0; j < 8; ++j) v.h[j] = (_Float16)W[(size_t)(k0 + j) * N + n];
    *(short8*)(ws + base + cp * 512 + lane * 8) = v.s;
}

// ---------------- activation LDS tile (per 16-row m-tile) — VERIFIED r3..r11 ----------------
// Element (row, k) at half-index (k>>2)*64 + (k&3)*16 + row.
// Store: lane (q,m) writes D rows q*4..q*4+3 of col ct*16+m as ONE ds_write_b64 at
//   ct*256 + (m>>2)*64 + (m&3)*16 + q*4.
// Read: ds_read_b64_tr_b16 at byte addr base + s*1024 + q*256 + m*8 (+offset:128)
//   delivers A[m][s*32 + q*8 + j], j=0..7.

__device__ __forceinline__ void lds_fence() {
    asm volatile("s_waitcnt lgkmcnt(0)" ::: "memory");
}

__device__ __forceinline__ half8 tr_read_ks(const _Float16* region, unsigned lane_off, int s) {
    h4_t lo, hi;
    asm volatile("ds_read_b64_tr_b16 %0, %2\n\t"
                 "ds_read_b64_tr_b16 %1, %2 offset:128"
                 : "=&v"(lo), "=&v"(hi)
                 : "v"((unsigned)(uintptr_t)region + lane_off + (unsigned)(s * 1024))
                 : "memory");
    return __builtin_shufflevector(lo, hi, 0, 1, 2, 3, 4, 5, 6, 7);
}

__device__ __forceinline__ void store_tile(_Float16* __restrict__ region, int ct_global,
                                           int m, int q, f32x4 v) {
    const int base = ct_global * 256 + (m >> 2) * 64 + (m & 3) * 16 + q * 4;
    pk2_t p0 = __builtin_amdgcn_cvt_pkrtz(v[0], v[1]);
    pk2_t p1 = __builtin_amdgcn_cvt_pkrtz(v[2], v[3]);
    h4_t h = {(_Float16)p0[0], (_Float16)p0[1], (_Float16)p1[0], (_Float16)p1[1]};
    h = __builtin_elementwise_max(h, (h4_t)(_Float16)0.0f);   // relu: 2x v_pk_max_f16
    *(h4_t*)(region + base) = h;       // ds_write_b64
}

// ---------------- half-layer: NC col-tiles (<=4), 2 m-tiles share every B fragment ----------
// acc[2][NC] is the ONLY live accumulator (32 AGPR max) — the register diet that buys
// 4 blocks/CU (r7: the single biggest verified win). Biases loaded just-in-time (L2-hot).
// B frags loaded per-slice: explicit double-buffering is collapsed by the compiler (r6),
// LDS-staging loses to occupancy (r1), gll-ring loses LDS budget (r10) — this simple
// form at max residency is the measured optimum of the explored space.
template <int NK, int NT, int NC>
__device__ __forceinline__ void layer_half(const half8* __restrict__ wf,
                                           const float* __restrict__ bias, int ct0,
                                           const half8 (&af)[2][4], int lane, int m,
                                           f32x4 (&acc)[2][4]) {
#pragma unroll
    for (int c = 0; c < NC; ++c) {
        const float b = bias[(ct0 + c) * 16 + m];
        acc[0][c] = f32x4{b, b, b, b};
        acc[1][c] = f32x4{b, b, b, b};
    }
#pragma unroll
    for (int s = 0; s < NK; ++s) {
        half8 bf[4];
#pragma unroll
        for (int c = 0; c < NC; ++c) bf[c] = wf[(s * NT + ct0 + c) * 64 + lane];
#pragma unroll
        for (int c = 0; c < NC; ++c) {
            acc[0][c] = MFMA16(af[0][s], bf[c], acc[0][c]);
            acc[1][c] = MFMA16(af[1][s], bf[c], acc[1][c]);
        }
    }
}

// One chunk (128 rows) per block — NO outer chunk loop: r11 showed a grid-stride loop
// around this body triggers ~230MB of scratch spill traffic (FETCH/WRITE x8).
__global__ __launch_bounds__(256, 4) void mlp_phi_mfma(
    const float* __restrict__ u,
    const float* __restrict__ b0, const float* __restrict__ b1,
    const float* __restrict__ b2, const float* __restrict__ b3,
    const short* __restrict__ ws,
    const float* __restrict__ var1, const float* __restrict__ var2,
    const float* __restrict__ var3, const float* __restrict__ var4,
    const float* __restrict__ var5, const float* __restrict__ var6,
    float* __restrict__ out) {
    // 4 waves/block, each wave owns 32 rows (two 16-row m-tiles) end-to-end.
    // No __syncthreads anywhere. LDS: 4 waves x 2 m-tile regions x 4 KB = 32 KB.
    __shared__ __align__(16) _Float16 lds[4 * 2 * REGION_HALFS];
    const int t = threadIdx.x, lane = t & 63, wave = t >> 6;
    const int m = lane & 15, q = lane >> 4;
    _Float16* lw = lds + wave * 2 * REGION_HALFS;
    const unsigned lane_rd = (unsigned)(q * 256 + m * 8);   // tr-read per-lane byte offset
    const size_t row0 = (size_t)blockIdx.x * 128 + wave * 32;

    const half8* wf0 = (const half8*)(ws);
    const half8* wf1 = (const half8*)(ws + 8192);
    const half8* wf2 = (const half8*)(ws + 24576);
    const half8* wf3 = (const half8*)(ws + 32768);

    half8 af[2][4];
    f32x4 acc[2][4];

    // ---- Layer 0 A-frags straight from global u (L3-hot), cvt_pkrtz fp32->f16 ----
#pragma unroll
    for (int mt = 0; mt < 2; ++mt) {
        const float* up = u + (row0 + mt * 16 + m) * 64;
#pragma unroll
        for (int s = 0; s < 2; ++s) {
            float4 v0a = *(const float4*)(up + s * 32 + q * 8);
            float4 v1a = *(const float4*)(up + s * 32 + q * 8 + 4);
            pk2_t p0 = __builtin_amdgcn_cvt_pkrtz(v0a.x, v0a.y);
            pk2_t p1 = __builtin_amdgcn_cvt_pkrtz(v0a.z, v0a.w);
            pk2_t p2 = __builtin_amdgcn_cvt_pkrtz(v1a.x, v1a.y);
            pk2_t p3 = __builtin_amdgcn_cvt_pkrtz(v1a.z, v1a.w);
            af[mt][s] = half8{(_Float16)p0[0], (_Float16)p0[1], (_Float16)p1[0], (_Float16)p1[1],
                              (_Float16)p2[0], (_Float16)p2[1], (_Float16)p3[0], (_Float16)p3[1]};
        }
    }

    // ---- Layer 0 (64 -> 128) in two 64-col halves ----
#pragma unroll
    for (int h = 0; h < 2; ++h) {
        layer_half<2, 8, 4>(wf0, b0, h * 4, af, lane, m, acc);
#pragma unroll
        for (int mt = 0; mt < 2; ++mt)
#pragma unroll
            for (int cc = 0; cc < 4; ++cc)
                store_tile(lw + mt * REGION_HALFS, h * 4 + cc, m, q, acc[mt][cc]);
    }
    lds_fence();
#pragma unroll
    for (int mt = 0; mt < 2; ++mt)
#pragma unroll
        for (int s = 0; s < 4; ++s) af[mt][s] = tr_read_ks(lw + mt * REGION_HALFS, lane_rd, s);
    lds_fence();
    __builtin_amdgcn_sched_barrier(0);   // rule 18: MFMA must not hoist above the wait

    // ---- Layer 1 (128 -> 128) in two 64-col halves ----
#pragma unroll
    for (int h = 0; h < 2; ++h) {
        layer_half<4, 8, 4>(wf1, b1, h * 4, af, lane, m, acc);
#pragma unroll
        for (int mt = 0; mt < 2; ++mt)
#pragma unroll
            for (int cc = 0; cc < 4; ++cc)
                store_tile(lw + mt * REGION_HALFS, h * 4 + cc, m, q, acc[mt][cc]);
    }
    lds_fence();
#pragma unroll
    for (int mt = 0; mt < 2; ++mt)
#pragma unroll
        for (int s = 0; s < 4; ++s) af[mt][s] = tr_read_ks(lw + mt * REGION_HALFS, lane_rd, s);
    lds_fence();
    __builtin_amdgcn_sched_barrier(0);

    // ---- Layer 2 (128 -> 64): single half (NT=4) ----
    layer_half<4, 4, 4>(wf2, b2, 0, af, lane, m, acc);
#pragma unroll
    for (int mt = 0; mt < 2; ++mt)
#pragma unroll
        for (int cc = 0; cc < 4; ++cc)
            store_tile(lw + mt * REGION_HALFS, cc, m, q, acc[mt][cc]);
    lds_fence();
#pragma unroll
    for (int mt = 0; mt < 2; ++mt)
#pragma unroll
        for (int s = 0; s < 2; ++s) af[mt][s] = tr_read_ks(lw + mt * REGION_HALFS, lane_rd, s);

    // Prefetch ALL epilogue u values now (r0/r6-validated): their scattered-load latency
    // hides under the final fence + layer-3 MFMAs instead of stalling the epilogue ALU.
    float ue[2][8];
#pragma unroll
    for (int mt = 0; mt < 2; ++mt)
#pragma unroll
        for (int ot = 0; ot < 2; ++ot)
#pragma unroll
            for (int r = 0; r < 4; ++r)
                ue[mt][ot * 4 + r] = u[(row0 + mt * 16 + q * 4 + r) * 64 + ot * 16 + m];

    lds_fence();
    __builtin_amdgcn_sched_barrier(0);

    // ---- Layer 3 (64 -> 32): net stays in registers (acc[mt][0..1]) ----
    layer_half<2, 2, 2>(wf3, b3, 0, af, lane, m, acc);

    // ---- Epilogue: lane holds net[row=mt*16+q*4+r][col=ot*16+m] ----
    // log2-domain: L = log2(1-u), ln2 folded into per-d constants; exp(-x) == omu
    // exactly (x = -log(1-u)) -> no __expf in the E1 large-x branch.
    // u in [1e-4, 1-1e-4] => all quantities finite in fp32 (nan_to_num is a no-op).
#pragma unroll
    for (int ot = 0; ot < 2; ++ot) {
        const int d = ot * 16 + m;
        const float v1 = var1[d], v6 = var6[d];
        const float v2p = var2[d] * INV_LN2_F;          // v2/ln2
        const float v4 = var4[d];
        const float v4p = v4 * INV_LN2_F;               // v4/ln2
        const float v5h = 0.5f * var5[d];
        const float v5hp = v5h * INV_LN2_F;             // v5h/ln2
        const float c3 = var3[d] - v4 - v5h;            // li coefficient
#pragma unroll
        for (int mt = 0; mt < 2; ++mt) {
#pragma unroll
            for (int r = 0; r < 4; ++r) {
                const size_t row = row0 + mt * 16 + q * 4 + r;
                const float net = acc[mt][ot][r];
                const float ud = ue[mt][ot * 4 + r];

                const float omu = 1.0f - ud;
                const float L = __log2f(omu);              // log2(1-u) < 0
                const float x = -L * LN2_F;                // -log(1-u), in (1e-4, 9.3)
                const float RL = __builtin_amdgcn_rcpf(L); // 1/log2(1-u)

                // E1 via Abramowitz-Stegun 5.1.53 (x<1) / 5.1.54 (x>=1)
                const float e1s = -__log2f(x) * LN2_F
                    + (-0.57721566f + x * (0.99999193f + x * (-0.24991055f
                    + x * (0.05519968f + x * (-0.00976004f + x * 0.00107857f)))));
                const float num = 0.2677737343f + x * (8.6347608925f + x * (18.0590169730f
                    + x * (8.5733287401f + x)));
                const float den = 3.9584969228f + x * (21.0996530827f + x * (25.6329561486f
                    + x * (9.5733223454f + x)));
                const float e1l = omu * num * __builtin_amdgcn_rcpf(x * den);  // exp(-x)=omu
                const float li = -((x < 1.0f) ? e1s : e1l); // _li(1-u)

                // phi = (v4*omu+v2)/lt + v5h*omu*(lt+1)/lt^2 + c3*li, log2 domain
                const float phi = fmaf(v4p, omu, v2p) * RL
                                + (v5hp * omu * (L + INV_LN2_F)) * RL * RL
                                + c3 * li;

                const float ud2 = ud * ud;
                const float ud4 = ud2 * ud2;
                const float p01 = ud4 * fmaf(-4.0f, ud, 5.0f);   // 5u^4 - 4u^5
                const float corr1 = p01 * (v1 + phi);
                const float d1 = ud - 1.0f;
                const float corr2 = v6 * ud * d1 * d1;           // u^3 - 2u^2 + u

                const float nt = fmaxf(net + corr1 + corr2, 0.0f);
                const float base = fmaf(-0.5f, ud2, 0.5f);       // (1-u^2)/2
                // base^(-nt) = exp2(-nt * log2(base)); v_exp_f32 is native exp2
                out[row * 32 + d] = __builtin_amdgcn_exp2f(-nt * __log2f(base));
            }
        }
    }
}

extern "C" void kernel_launch(void* const* d_in, const int* in_sizes, int n_in,
                              void* d_out, int out_size, void* d_ws, size_t ws_size,
                              hipStream_t stream) {
    const float* u    = (const float*)d_in[0];
    const float* W0   = (const float*)d_in[1];
    const float* b0   = (const float*)d_in[2];
    const float* W1   = (const float*)d_in[3];
    const float* b1   = (const float*)d_in[4];
    const float* W2   = (const float*)d_in[5];
    const float* b2   = (const float*)d_in[6];
    const float* W3   = (const float*)d_in[7];
    const float* b3   = (const float*)d_in[8];
    const float* var1 = (const float*)d_in[9];
    const float* var2 = (const float*)d_in[10];
    const float* var3 = (const float*)d_in[11];
    const float* var4 = (const float*)d_in[12];
    const float* var5 = (const float*)d_in[13];
    const float* var6 = (const float*)d_in[14];
    float* out = (float*)d_out;
    short* ws = (short*)d_ws;   // needs 69,632 B

    // Convert weights to f16 fragment layout (same work every launch).
    prep_weights<<<dim3(17), dim3(256), 0, stream>>>(W0, W1, W2, W3, ws);

    const int B = in_sizes[0] / 64;        // 262144 rows
    const int blocks = B / 128;            // 128 rows per block (32 per wave)
    mlp_phi_mfma<<<dim3(blocks), dim3(256), 0, stream>>>(
        u, b0, b1, b2, b3, ws,
        var1, var2, var3, var4, var5, var6, out);
}